// Round 1
// baseline (251.398 us; speedup 1.0000x reference)
//
#include <hip/hip_runtime.h>

#define HW_ (768 * 1024)
#define W_ 1024
#define DC 0.867f
#define DD 0.005f
#define DZ 0.0001f

__global__ __launch_bounds__(256) void vn_main(
    const float* __restrict__ gt, const float* __restrict__ pred,
    const int* __restrict__ p1x, const int* __restrict__ p1y,
    const int* __restrict__ p2x, const int* __restrict__ p2y,
    const int* __restrict__ p3x, const int* __restrict__ p3y,
    int G, double* __restrict__ acc)
{
    int g = blockIdx.x * 256 + threadIdx.x;
    int b = blockIdx.y;

    float s_loss = 0.f, s_cnt = 0.f;

    if (g < G) {
        int o1 = p1y[g] * W_ + p1x[g];
        int o2 = p2y[g] * W_ + p2x[g];
        int o3 = p3y[g] * W_ + p3x[g];
        const float* gb = gt   + (size_t)b * 3 * HW_;
        const float* pb = pred + (size_t)b * 3 * HW_;

        float G1[3], G2[3], G3[3], P1[3], P2[3], P3[3];
        #pragma unroll
        for (int c = 0; c < 3; c++) {
            G1[c] = gb[c * HW_ + o1];
            G2[c] = gb[c * HW_ + o2];
            G3[c] = gb[c * HW_ + o3];
            P1[c] = pb[c * HW_ + o1];
            P2[c] = pb[c * HW_ + o2];
            P3[c] = pb[c * HW_ + o3];
        }

        // gt diffs: d0 = p2-p1 (12), d1 = p3-p1 (13), d2 = p3-p2 (23)
        float d0[3], d1[3], d2[3];
        #pragma unroll
        for (int c = 0; c < 3; c++) {
            d0[c] = G2[c] - G1[c];
            d1[c] = G3[c] - G1[c];
            d2[c] = G3[c] - G2[c];
        }

        float e00 = d0[0]*d0[0] + d0[1]*d0[1] + d0[2]*d0[2];
        float e11 = d1[0]*d1[0] + d1[1]*d1[1] + d1[2]*d1[2];
        float e22 = d2[0]*d2[0] + d2[1]*d2[1] + d2[2]*d2[2];
        float e01 = d0[0]*d1[0] + d0[1]*d1[1] + d0[2]*d1[2];
        float e02 = d0[0]*d2[0] + d0[1]*d2[1] + d0[2]*d2[2];
        float e12 = d1[0]*d2[0] + d1[1]*d2[1] + d1[2]*d2[2];
        float s0 = sqrtf(e00), s1 = sqrtf(e11), s2 = sqrtf(e22);

        // count of |norm_energy| > DC over full 3x3 (off-diag counted twice)
        int cc = 0;
        {
            float ne;
            ne = e00 / (s0*s0 + 1e-8f); cc += (ne > DC) || (ne < -DC);
            ne = e11 / (s1*s1 + 1e-8f); cc += (ne > DC) || (ne < -DC);
            ne = e22 / (s2*s2 + 1e-8f); cc += (ne > DC) || (ne < -DC);
            ne = e01 / (s0*s1 + 1e-8f); cc += 2 * ((ne > DC) || (ne < -DC));
            ne = e02 / (s0*s2 + 1e-8f); cc += 2 * ((ne > DC) || (ne < -DC));
            ne = e12 / (s1*s2 + 1e-8f); cc += 2 * ((ne > DC) || (ne < -DC));
        }
        bool mask_cos = cc > 3;
        bool mask_pad = (G1[2] > DZ) && (G2[2] > DZ) && (G3[2] > DZ);
        bool mx = (fabsf(d0[0]) < DD) || (fabsf(d1[0]) < DD) || (fabsf(d2[0]) < DD);
        bool my = (fabsf(d0[1]) < DD) || (fabsf(d1[1]) < DD) || (fabsf(d2[1]) < DD);
        bool mz = (fabsf(d0[2]) < DD) || (fabsf(d1[2]) < DD) || (fabsf(d2[2]) < DD);
        bool mask = mask_pad && !((mx && my && mz) || mask_cos);

        if (mask) {
            // gt normal from cross(d0, d1)
            float n0 = d0[1]*d1[2] - d0[2]*d1[1];
            float n1 = d0[2]*d1[0] - d0[0]*d1[2];
            float n2 = d0[0]*d1[1] - d0[1]*d1[0];
            float nn = sqrtf(n0*n0 + n1*n1 + n2*n2);
            if (nn == 0.f) nn = 0.01f;

            // pred z-fix: bug-faithful broadcast — zmask indexed by POINT p,
            // applied along the CHANNEL axis c (= the reference's zmask[:,:,:,None]
            // broadcast against pw_gp (B,G,c,p)).
            bool zm[3] = { P1[2] == 0.f, P2[2] == 0.f, P3[2] == 0.f };
            float Q1[3], Q2[3], Q3[3];
            #pragma unroll
            for (int c = 0; c < 3; c++) {
                Q1[c] = zm[c] ? 0.0001f : P1[c];
                Q2[c] = zm[c] ? 0.0001f : P2[c];
                Q3[c] = zm[c] ? 0.0001f : P3[c];
            }
            float q0[3], q1[3];
            #pragma unroll
            for (int c = 0; c < 3; c++) {
                q0[c] = Q2[c] - Q1[c];
                q1[c] = Q3[c] - Q1[c];
            }
            float m0 = q0[1]*q1[2] - q0[2]*q1[1];
            float m1 = q0[2]*q1[0] - q0[0]*q1[2];
            float m2 = q0[0]*q1[1] - q0[1]*q1[0];
            float mn = sqrtf(m0*m0 + m1*m1 + m2*m2);
            if (mn == 0.f) mn = 0.01f;

            float pg = fabsf(n0/nn - m0/mn) + fabsf(n1/nn - m1/mn) + fabsf(n2/nn - m2/mn);
            s_loss = pg;
            s_cnt  = 1.f;
        }
    }

    // wave64 reduce
    #pragma unroll
    for (int off = 32; off > 0; off >>= 1) {
        s_loss += __shfl_down(s_loss, off);
        s_cnt  += __shfl_down(s_cnt,  off);
    }

    __shared__ float ls[4], lc[4];
    int lane = threadIdx.x & 63;
    int wid  = threadIdx.x >> 6;
    if (lane == 0) { ls[wid] = s_loss; lc[wid] = s_cnt; }
    __syncthreads();
    if (threadIdx.x == 0) {
        float tl = ls[0] + ls[1] + ls[2] + ls[3];
        float tc = lc[0] + lc[1] + lc[2] + lc[3];
        atomicAdd(acc,     (double)tl);
        atomicAdd(acc + 1, (double)tc);
    }
}

__global__ void vn_final(const double* __restrict__ acc, float* __restrict__ out)
{
    float s = (float)acc[0];
    float c = (float)acc[1];
    out[0] = s / fmaxf(c, 1.0f);
}

extern "C" void kernel_launch(void* const* d_in, const int* in_sizes, int n_in,
                              void* d_out, int out_size, void* d_ws, size_t ws_size,
                              hipStream_t stream) {
    const float* gt   = (const float*)d_in[0];
    const float* pred = (const float*)d_in[1];
    const int* p1x = (const int*)d_in[2];
    const int* p1y = (const int*)d_in[3];
    const int* p2x = (const int*)d_in[4];
    const int* p2y = (const int*)d_in[5];
    const int* p3x = (const int*)d_in[6];
    const int* p3y = (const int*)d_in[7];

    int G = in_sizes[2];
    int B = in_sizes[0] / (3 * HW_);
    double* acc = (double*)d_ws;

    hipMemsetAsync(acc, 0, 2 * sizeof(double), stream);

    dim3 grid((G + 255) / 256, B);
    vn_main<<<grid, 256, 0, stream>>>(gt, pred, p1x, p1y, p2x, p2y, p3x, p3y, G, acc);
    vn_final<<<1, 1, 0, stream>>>(acc, (float*)d_out);
}

// Round 2
// 202.466 us; speedup vs baseline: 1.2417x; 1.2417x over previous
//
#include <hip/hip_runtime.h>

#define HW_ (768 * 1024)
#define W_ 1024
#define DC 0.867f
#define DD 0.005f
#define DZ 0.0001f

// ---------------- pack: plane-major (b,c,h,w) -> pixel-major 32B records ----
// rec[b][i] = {gt0, gt1, gt2, pr0, pr1, pr2, pad, pad}  (two float4s)
__global__ __launch_bounds__(256) void vn_pack(
    const float* __restrict__ gt, const float* __restrict__ pred,
    float4* __restrict__ rec)
{
    int b = blockIdx.y;
    size_t i = ((size_t)blockIdx.x * 256 + threadIdx.x) * 4;   // 4 pixels/thread
    const float* gb = gt   + (size_t)b * 3 * HW_;
    const float* pb = pred + (size_t)b * 3 * HW_;

    float4 a0 = *(const float4*)(gb + i);
    float4 a1 = *(const float4*)(gb + HW_ + i);
    float4 a2 = *(const float4*)(gb + 2 * (size_t)HW_ + i);
    float4 b0 = *(const float4*)(pb + i);
    float4 b1 = *(const float4*)(pb + HW_ + i);
    float4 b2 = *(const float4*)(pb + 2 * (size_t)HW_ + i);

    float4* out = rec + ((size_t)b * HW_ + i) * 2;
    out[0] = make_float4(a0.x, a1.x, a2.x, b0.x);
    out[1] = make_float4(b1.x, b2.x, 0.f, 0.f);
    out[2] = make_float4(a0.y, a1.y, a2.y, b0.y);
    out[3] = make_float4(b1.y, b2.y, 0.f, 0.f);
    out[4] = make_float4(a0.z, a1.z, a2.z, b0.z);
    out[5] = make_float4(b1.z, b2.z, 0.f, 0.f);
    out[6] = make_float4(a0.w, a1.w, a2.w, b0.w);
    out[7] = make_float4(b1.w, b2.w, 0.f, 0.f);
}

// ---------------- shared group math --------------------------------------
__device__ __forceinline__ void vn_group_math(
    const float G1[3], const float G2[3], const float G3[3],
    const float P1[3], const float P2[3], const float P3[3],
    float& s_loss, float& s_cnt)
{
    float d0[3], d1[3], d2[3];
    #pragma unroll
    for (int c = 0; c < 3; c++) {
        d0[c] = G2[c] - G1[c];
        d1[c] = G3[c] - G1[c];
        d2[c] = G3[c] - G2[c];
    }

    float e00 = d0[0]*d0[0] + d0[1]*d0[1] + d0[2]*d0[2];
    float e11 = d1[0]*d1[0] + d1[1]*d1[1] + d1[2]*d1[2];
    float e22 = d2[0]*d2[0] + d2[1]*d2[1] + d2[2]*d2[2];
    float e01 = d0[0]*d1[0] + d0[1]*d1[1] + d0[2]*d1[2];
    float e02 = d0[0]*d2[0] + d0[1]*d2[1] + d0[2]*d2[2];
    float e12 = d1[0]*d2[0] + d1[1]*d2[1] + d1[2]*d2[2];
    float s0 = sqrtf(e00), s1 = sqrtf(e11), s2 = sqrtf(e22);

    int cc = 0;
    {
        float ne;
        ne = e00 / (s0*s0 + 1e-8f); cc += (ne > DC) || (ne < -DC);
        ne = e11 / (s1*s1 + 1e-8f); cc += (ne > DC) || (ne < -DC);
        ne = e22 / (s2*s2 + 1e-8f); cc += (ne > DC) || (ne < -DC);
        ne = e01 / (s0*s1 + 1e-8f); cc += 2 * ((ne > DC) || (ne < -DC));
        ne = e02 / (s0*s2 + 1e-8f); cc += 2 * ((ne > DC) || (ne < -DC));
        ne = e12 / (s1*s2 + 1e-8f); cc += 2 * ((ne > DC) || (ne < -DC));
    }
    bool mask_cos = cc > 3;
    bool mask_pad = (G1[2] > DZ) && (G2[2] > DZ) && (G3[2] > DZ);
    bool mx = (fabsf(d0[0]) < DD) || (fabsf(d1[0]) < DD) || (fabsf(d2[0]) < DD);
    bool my = (fabsf(d0[1]) < DD) || (fabsf(d1[1]) < DD) || (fabsf(d2[1]) < DD);
    bool mz = (fabsf(d0[2]) < DD) || (fabsf(d1[2]) < DD) || (fabsf(d2[2]) < DD);
    bool mask = mask_pad && !((mx && my && mz) || mask_cos);

    if (mask) {
        float n0 = d0[1]*d1[2] - d0[2]*d1[1];
        float n1 = d0[2]*d1[0] - d0[0]*d1[2];
        float n2 = d0[0]*d1[1] - d0[1]*d1[0];
        float nn = sqrtf(n0*n0 + n1*n1 + n2*n2);
        if (nn == 0.f) nn = 0.01f;

        // bug-faithful zmask broadcast: mask indexed by POINT, applied on CHANNEL
        bool zm[3] = { P1[2] == 0.f, P2[2] == 0.f, P3[2] == 0.f };
        float Q1[3], Q2[3], Q3[3];
        #pragma unroll
        for (int c = 0; c < 3; c++) {
            Q1[c] = zm[c] ? 0.0001f : P1[c];
            Q2[c] = zm[c] ? 0.0001f : P2[c];
            Q3[c] = zm[c] ? 0.0001f : P3[c];
        }
        float q0[3], q1[3];
        #pragma unroll
        for (int c = 0; c < 3; c++) {
            q0[c] = Q2[c] - Q1[c];
            q1[c] = Q3[c] - Q1[c];
        }
        float m0 = q0[1]*q1[2] - q0[2]*q1[1];
        float m1 = q0[2]*q1[0] - q0[0]*q1[2];
        float m2 = q0[0]*q1[1] - q0[1]*q1[0];
        float mn = sqrtf(m0*m0 + m1*m1 + m2*m2);
        if (mn == 0.f) mn = 0.01f;

        s_loss = fabsf(n0/nn - m0/mn) + fabsf(n1/nn - m1/mn) + fabsf(n2/nn - m2/mn);
        s_cnt  = 1.f;
    }
}

__device__ __forceinline__ void vn_reduce_store(float s_loss, float s_cnt, double* acc)
{
    #pragma unroll
    for (int off = 32; off > 0; off >>= 1) {
        s_loss += __shfl_down(s_loss, off);
        s_cnt  += __shfl_down(s_cnt,  off);
    }
    __shared__ float ls[4], lc[4];
    int lane = threadIdx.x & 63;
    int wid  = threadIdx.x >> 6;
    if (lane == 0) { ls[wid] = s_loss; lc[wid] = s_cnt; }
    __syncthreads();
    if (threadIdx.x == 0) {
        float tl = ls[0] + ls[1] + ls[2] + ls[3];
        float tc = lc[0] + lc[1] + lc[2] + lc[3];
        atomicAdd(acc,     (double)tl);
        atomicAdd(acc + 1, (double)tc);
    }
}

// ---------------- gather from packed records ------------------------------
__global__ __launch_bounds__(256) void vn_gather(
    const float4* __restrict__ rec,
    const int* __restrict__ p1x, const int* __restrict__ p1y,
    const int* __restrict__ p2x, const int* __restrict__ p2y,
    const int* __restrict__ p3x, const int* __restrict__ p3y,
    int G, double* __restrict__ acc)
{
    int g = blockIdx.x * 256 + threadIdx.x;
    int b = blockIdx.y;

    float s_loss = 0.f, s_cnt = 0.f;

    if (g < G) {
        size_t base = (size_t)b * HW_;
        size_t o1 = base + (size_t)(p1y[g] * W_ + p1x[g]);
        size_t o2 = base + (size_t)(p2y[g] * W_ + p2x[g]);
        size_t o3 = base + (size_t)(p3y[g] * W_ + p3x[g]);

        float4 r1a = rec[o1*2], r1b = rec[o1*2+1];
        float4 r2a = rec[o2*2], r2b = rec[o2*2+1];
        float4 r3a = rec[o3*2], r3b = rec[o3*2+1];

        float G1[3] = {r1a.x, r1a.y, r1a.z}, P1[3] = {r1a.w, r1b.x, r1b.y};
        float G2[3] = {r2a.x, r2a.y, r2a.z}, P2[3] = {r2a.w, r2b.x, r2b.y};
        float G3[3] = {r3a.x, r3a.y, r3a.z}, P3[3] = {r3a.w, r3b.x, r3b.y};

        vn_group_math(G1, G2, G3, P1, P2, P3, s_loss, s_cnt);
    }

    vn_reduce_store(s_loss, s_cnt, acc);
}

// ---------------- fallback: direct gather from plane-major ---------------
__global__ __launch_bounds__(256) void vn_main(
    const float* __restrict__ gt, const float* __restrict__ pred,
    const int* __restrict__ p1x, const int* __restrict__ p1y,
    const int* __restrict__ p2x, const int* __restrict__ p2y,
    const int* __restrict__ p3x, const int* __restrict__ p3y,
    int G, double* __restrict__ acc)
{
    int g = blockIdx.x * 256 + threadIdx.x;
    int b = blockIdx.y;

    float s_loss = 0.f, s_cnt = 0.f;

    if (g < G) {
        int o1 = p1y[g] * W_ + p1x[g];
        int o2 = p2y[g] * W_ + p2x[g];
        int o3 = p3y[g] * W_ + p3x[g];
        const float* gb = gt   + (size_t)b * 3 * HW_;
        const float* pb = pred + (size_t)b * 3 * HW_;

        float G1[3], G2[3], G3[3], P1[3], P2[3], P3[3];
        #pragma unroll
        for (int c = 0; c < 3; c++) {
            G1[c] = gb[c * HW_ + o1];
            G2[c] = gb[c * HW_ + o2];
            G3[c] = gb[c * HW_ + o3];
            P1[c] = pb[c * HW_ + o1];
            P2[c] = pb[c * HW_ + o2];
            P3[c] = pb[c * HW_ + o3];
        }
        vn_group_math(G1, G2, G3, P1, P2, P3, s_loss, s_cnt);
    }

    vn_reduce_store(s_loss, s_cnt, acc);
}

__global__ void vn_final(const double* __restrict__ acc, float* __restrict__ out)
{
    float s = (float)acc[0];
    float c = (float)acc[1];
    out[0] = s / fmaxf(c, 1.0f);
}

extern "C" void kernel_launch(void* const* d_in, const int* in_sizes, int n_in,
                              void* d_out, int out_size, void* d_ws, size_t ws_size,
                              hipStream_t stream) {
    const float* gt   = (const float*)d_in[0];
    const float* pred = (const float*)d_in[1];
    const int* p1x = (const int*)d_in[2];
    const int* p1y = (const int*)d_in[3];
    const int* p2x = (const int*)d_in[4];
    const int* p2y = (const int*)d_in[5];
    const int* p3x = (const int*)d_in[6];
    const int* p3y = (const int*)d_in[7];

    int G = in_sizes[2];
    int B = in_sizes[0] / (3 * HW_);
    double* acc = (double*)d_ws;

    hipMemsetAsync(acc, 0, 2 * sizeof(double), stream);

    size_t rec_bytes = (size_t)B * HW_ * 8 * sizeof(float);   // 32B per pixel
    size_t need = 256 + rec_bytes;

    if (ws_size >= need) {
        float4* rec = (float4*)((char*)d_ws + 256);
        dim3 pgrid(HW_ / (256 * 4), B);                        // 4 pixels/thread
        vn_pack<<<pgrid, 256, 0, stream>>>(gt, pred, rec);
        dim3 ggrid((G + 255) / 256, B);
        vn_gather<<<ggrid, 256, 0, stream>>>(rec, p1x, p1y, p2x, p2y, p3x, p3y, G, acc);
    } else {
        dim3 grid((G + 255) / 256, B);
        vn_main<<<grid, 256, 0, stream>>>(gt, pred, p1x, p1y, p2x, p2y, p3x, p3y, G, acc);
    }

    vn_final<<<1, 1, 0, stream>>>(acc, (float*)d_out);
}

// Round 3
// 166.369 us; speedup vs baseline: 1.5111x; 1.2170x over previous
//
#include <hip/hip_runtime.h>

#define HW_ (768 * 1024)
#define W_ 1024
#define DC 0.867f
#define DD 0.005f
#define DZ 0.0001f

typedef float f4v __attribute__((ext_vector_type(4)));

__device__ __forceinline__ f4v ntload4(const float* p) {
    return __builtin_nontemporal_load((const f4v*)p);
}

// ---------------- pack: plane-major (b,c,h,w) -> pixel-major 32B records ----
// rec[b][i] = {gt0, gt1, gt2, pr0, pr1, pr2, pad, pad}  (two float4s)
// Reads are NONTEMPORAL (nt): keep the 201MB record write-set L3-resident so
// the gather hits L3 instead of random HBM lines.
__global__ __launch_bounds__(256) void vn_pack(
    const float* __restrict__ gt, const float* __restrict__ pred,
    float4* __restrict__ rec)
{
    int b = blockIdx.y;
    size_t i = ((size_t)blockIdx.x * 256 + threadIdx.x) * 4;   // 4 pixels/thread
    const float* gb = gt   + (size_t)b * 3 * HW_;
    const float* pb = pred + (size_t)b * 3 * HW_;

    f4v a0 = ntload4(gb + i);
    f4v a1 = ntload4(gb + HW_ + i);
    f4v a2 = ntload4(gb + 2 * (size_t)HW_ + i);
    f4v b0 = ntload4(pb + i);
    f4v b1 = ntload4(pb + HW_ + i);
    f4v b2 = ntload4(pb + 2 * (size_t)HW_ + i);

    float4* out = rec + ((size_t)b * HW_ + i) * 2;
    out[0] = make_float4(a0.x, a1.x, a2.x, b0.x);
    out[1] = make_float4(b1.x, b2.x, 0.f, 0.f);
    out[2] = make_float4(a0.y, a1.y, a2.y, b0.y);
    out[3] = make_float4(b1.y, b2.y, 0.f, 0.f);
    out[4] = make_float4(a0.z, a1.z, a2.z, b0.z);
    out[5] = make_float4(b1.z, b2.z, 0.f, 0.f);
    out[6] = make_float4(a0.w, a1.w, a2.w, b0.w);
    out[7] = make_float4(b1.w, b2.w, 0.f, 0.f);
}

// ---------------- shared group math --------------------------------------
__device__ __forceinline__ void vn_group_math(
    const float G1[3], const float G2[3], const float G3[3],
    const float P1[3], const float P2[3], const float P3[3],
    float& s_loss, float& s_cnt)
{
    float d0[3], d1[3], d2[3];
    #pragma unroll
    for (int c = 0; c < 3; c++) {
        d0[c] = G2[c] - G1[c];
        d1[c] = G3[c] - G1[c];
        d2[c] = G3[c] - G2[c];
    }

    float e00 = d0[0]*d0[0] + d0[1]*d0[1] + d0[2]*d0[2];
    float e11 = d1[0]*d1[0] + d1[1]*d1[1] + d1[2]*d1[2];
    float e22 = d2[0]*d2[0] + d2[1]*d2[1] + d2[2]*d2[2];
    float e01 = d0[0]*d1[0] + d0[1]*d1[1] + d0[2]*d1[2];
    float e02 = d0[0]*d2[0] + d0[1]*d2[1] + d0[2]*d2[2];
    float e12 = d1[0]*d2[0] + d1[1]*d2[1] + d1[2]*d2[2];
    float s0 = sqrtf(e00), s1 = sqrtf(e11), s2 = sqrtf(e22);

    int cc = 0;
    {
        float ne;
        ne = e00 / (s0*s0 + 1e-8f); cc += (ne > DC) || (ne < -DC);
        ne = e11 / (s1*s1 + 1e-8f); cc += (ne > DC) || (ne < -DC);
        ne = e22 / (s2*s2 + 1e-8f); cc += (ne > DC) || (ne < -DC);
        ne = e01 / (s0*s1 + 1e-8f); cc += 2 * ((ne > DC) || (ne < -DC));
        ne = e02 / (s0*s2 + 1e-8f); cc += 2 * ((ne > DC) || (ne < -DC));
        ne = e12 / (s1*s2 + 1e-8f); cc += 2 * ((ne > DC) || (ne < -DC));
    }
    bool mask_cos = cc > 3;
    bool mask_pad = (G1[2] > DZ) && (G2[2] > DZ) && (G3[2] > DZ);
    bool mx = (fabsf(d0[0]) < DD) || (fabsf(d1[0]) < DD) || (fabsf(d2[0]) < DD);
    bool my = (fabsf(d0[1]) < DD) || (fabsf(d1[1]) < DD) || (fabsf(d2[1]) < DD);
    bool mz = (fabsf(d0[2]) < DD) || (fabsf(d1[2]) < DD) || (fabsf(d2[2]) < DD);
    bool mask = mask_pad && !((mx && my && mz) || mask_cos);

    if (mask) {
        float n0 = d0[1]*d1[2] - d0[2]*d1[1];
        float n1 = d0[2]*d1[0] - d0[0]*d1[2];
        float n2 = d0[0]*d1[1] - d0[1]*d1[0];
        float nn = sqrtf(n0*n0 + n1*n1 + n2*n2);
        if (nn == 0.f) nn = 0.01f;

        // bug-faithful zmask broadcast: mask indexed by POINT, applied on CHANNEL
        bool zm[3] = { P1[2] == 0.f, P2[2] == 0.f, P3[2] == 0.f };
        float Q1[3], Q2[3], Q3[3];
        #pragma unroll
        for (int c = 0; c < 3; c++) {
            Q1[c] = zm[c] ? 0.0001f : P1[c];
            Q2[c] = zm[c] ? 0.0001f : P2[c];
            Q3[c] = zm[c] ? 0.0001f : P3[c];
        }
        float q0[3], q1[3];
        #pragma unroll
        for (int c = 0; c < 3; c++) {
            q0[c] = Q2[c] - Q1[c];
            q1[c] = Q3[c] - Q1[c];
        }
        float m0 = q0[1]*q1[2] - q0[2]*q1[1];
        float m1 = q0[2]*q1[0] - q0[0]*q1[2];
        float m2 = q0[0]*q1[1] - q0[1]*q1[0];
        float mn = sqrtf(m0*m0 + m1*m1 + m2*m2);
        if (mn == 0.f) mn = 0.01f;

        s_loss = fabsf(n0/nn - m0/mn) + fabsf(n1/nn - m1/mn) + fabsf(n2/nn - m2/mn);
        s_cnt  = 1.f;
    }
}

__device__ __forceinline__ void vn_reduce_store(float s_loss, float s_cnt, double* acc)
{
    #pragma unroll
    for (int off = 32; off > 0; off >>= 1) {
        s_loss += __shfl_down(s_loss, off);
        s_cnt  += __shfl_down(s_cnt,  off);
    }
    __shared__ float ls[4], lc[4];
    int lane = threadIdx.x & 63;
    int wid  = threadIdx.x >> 6;
    if (lane == 0) { ls[wid] = s_loss; lc[wid] = s_cnt; }
    __syncthreads();
    if (threadIdx.x == 0) {
        float tl = ls[0] + ls[1] + ls[2] + ls[3];
        float tc = lc[0] + lc[1] + lc[2] + lc[3];
        atomicAdd(acc,     (double)tl);
        atomicAdd(acc + 1, (double)tc);
    }
}

// ---------------- gather from packed records (2 groups/thread for MLP) -----
__global__ __launch_bounds__(256) void vn_gather(
    const float4* __restrict__ rec,
    const int* __restrict__ p1x, const int* __restrict__ p1y,
    const int* __restrict__ p2x, const int* __restrict__ p2y,
    const int* __restrict__ p3x, const int* __restrict__ p3y,
    int G, double* __restrict__ acc)
{
    int g0 = blockIdx.x * 512 + threadIdx.x;
    int g1 = g0 + 256;
    int b  = blockIdx.y;
    size_t base = (size_t)b * HW_;

    float s_loss = 0.f, s_cnt = 0.f;

    // issue all index loads + record loads for both groups up front (MLP)
    float4 r1a0, r1b0, r2a0, r2b0, r3a0, r3b0;
    float4 r1a1, r1b1, r2a1, r2b1, r3a1, r3b1;
    bool v0 = g0 < G, v1 = g1 < G;

    if (v0) {
        size_t o1 = base + (size_t)(p1y[g0] * W_ + p1x[g0]);
        size_t o2 = base + (size_t)(p2y[g0] * W_ + p2x[g0]);
        size_t o3 = base + (size_t)(p3y[g0] * W_ + p3x[g0]);
        r1a0 = rec[o1*2]; r1b0 = rec[o1*2+1];
        r2a0 = rec[o2*2]; r2b0 = rec[o2*2+1];
        r3a0 = rec[o3*2]; r3b0 = rec[o3*2+1];
    }
    if (v1) {
        size_t o1 = base + (size_t)(p1y[g1] * W_ + p1x[g1]);
        size_t o2 = base + (size_t)(p2y[g1] * W_ + p2x[g1]);
        size_t o3 = base + (size_t)(p3y[g1] * W_ + p3x[g1]);
        r1a1 = rec[o1*2]; r1b1 = rec[o1*2+1];
        r2a1 = rec[o2*2]; r2b1 = rec[o2*2+1];
        r3a1 = rec[o3*2]; r3b1 = rec[o3*2+1];
    }

    if (v0) {
        float G1[3] = {r1a0.x, r1a0.y, r1a0.z}, P1[3] = {r1a0.w, r1b0.x, r1b0.y};
        float G2[3] = {r2a0.x, r2a0.y, r2a0.z}, P2[3] = {r2a0.w, r2b0.x, r2b0.y};
        float G3[3] = {r3a0.x, r3a0.y, r3a0.z}, P3[3] = {r3a0.w, r3b0.x, r3b0.y};
        vn_group_math(G1, G2, G3, P1, P2, P3, s_loss, s_cnt);
    }
    if (v1) {
        float l = 0.f, c = 0.f;
        float G1[3] = {r1a1.x, r1a1.y, r1a1.z}, P1[3] = {r1a1.w, r1b1.x, r1b1.y};
        float G2[3] = {r2a1.x, r2a1.y, r2a1.z}, P2[3] = {r2a1.w, r2b1.x, r2b1.y};
        float G3[3] = {r3a1.x, r3a1.y, r3a1.z}, P3[3] = {r3a1.w, r3b1.x, r3b1.y};
        vn_group_math(G1, G2, G3, P1, P2, P3, l, c);
        s_loss += l; s_cnt += c;
    }

    vn_reduce_store(s_loss, s_cnt, acc);
}

// ---------------- fallback: direct gather from plane-major ---------------
__global__ __launch_bounds__(256) void vn_main(
    const float* __restrict__ gt, const float* __restrict__ pred,
    const int* __restrict__ p1x, const int* __restrict__ p1y,
    const int* __restrict__ p2x, const int* __restrict__ p2y,
    const int* __restrict__ p3x, const int* __restrict__ p3y,
    int G, double* __restrict__ acc)
{
    int g = blockIdx.x * 256 + threadIdx.x;
    int b = blockIdx.y;

    float s_loss = 0.f, s_cnt = 0.f;

    if (g < G) {
        int o1 = p1y[g] * W_ + p1x[g];
        int o2 = p2y[g] * W_ + p2x[g];
        int o3 = p3y[g] * W_ + p3x[g];
        const float* gb = gt   + (size_t)b * 3 * HW_;
        const float* pb = pred + (size_t)b * 3 * HW_;

        float G1[3], G2[3], G3[3], P1[3], P2[3], P3[3];
        #pragma unroll
        for (int c = 0; c < 3; c++) {
            G1[c] = gb[c * HW_ + o1];
            G2[c] = gb[c * HW_ + o2];
            G3[c] = gb[c * HW_ + o3];
            P1[c] = pb[c * HW_ + o1];
            P2[c] = pb[c * HW_ + o2];
            P3[c] = pb[c * HW_ + o3];
        }
        vn_group_math(G1, G2, G3, P1, P2, P3, s_loss, s_cnt);
    }

    vn_reduce_store(s_loss, s_cnt, acc);
}

__global__ void vn_final(const double* __restrict__ acc, float* __restrict__ out)
{
    float s = (float)acc[0];
    float c = (float)acc[1];
    out[0] = s / fmaxf(c, 1.0f);
}

extern "C" void kernel_launch(void* const* d_in, const int* in_sizes, int n_in,
                              void* d_out, int out_size, void* d_ws, size_t ws_size,
                              hipStream_t stream) {
    const float* gt   = (const float*)d_in[0];
    const float* pred = (const float*)d_in[1];
    const int* p1x = (const int*)d_in[2];
    const int* p1y = (const int*)d_in[3];
    const int* p2x = (const int*)d_in[4];
    const int* p2y = (const int*)d_in[5];
    const int* p3x = (const int*)d_in[6];
    const int* p3y = (const int*)d_in[7];

    int G = in_sizes[2];
    int B = in_sizes[0] / (3 * HW_);
    double* acc = (double*)d_ws;

    hipMemsetAsync(acc, 0, 2 * sizeof(double), stream);

    size_t rec_bytes = (size_t)B * HW_ * 8 * sizeof(float);   // 32B per pixel
    size_t need = 256 + rec_bytes;

    if (ws_size >= need) {
        float4* rec = (float4*)((char*)d_ws + 256);
        dim3 pgrid(HW_ / (256 * 4), B);                        // 4 pixels/thread
        vn_pack<<<pgrid, 256, 0, stream>>>(gt, pred, rec);
        dim3 ggrid((G + 511) / 512, B);                        // 2 groups/thread
        vn_gather<<<ggrid, 256, 0, stream>>>(rec, p1x, p1y, p2x, p2y, p3x, p3y, G, acc);
    } else {
        dim3 grid((G + 255) / 256, B);
        vn_main<<<grid, 256, 0, stream>>>(gt, pred, p1x, p1y, p2x, p2y, p3x, p3y, G, acc);
    }

    vn_final<<<1, 1, 0, stream>>>(acc, (float*)d_out);
}

// Round 4
// 83.304 us; speedup vs baseline: 3.0178x; 1.9971x over previous
//
#include <hip/hip_runtime.h>
#include <hip/hip_fp16.h>

#define HW_ (768 * 1024)
#define W_ 1024
#define DC 0.867f
#define DD 0.005f
#define DZ 0.0001f

// ---------------- shared group math (ACCUMULATES into s_loss/s_cnt) -------
__device__ __forceinline__ void vn_group_math(
    const float G1[3], const float G2[3], const float G3[3],
    const float P1[3], const float P2[3], const float P3[3],
    float& s_loss, float& s_cnt)
{
    float d0[3], d1[3], d2[3];
    #pragma unroll
    for (int c = 0; c < 3; c++) {
        d0[c] = G2[c] - G1[c];
        d1[c] = G3[c] - G1[c];
        d2[c] = G3[c] - G2[c];
    }

    float e00 = d0[0]*d0[0] + d0[1]*d0[1] + d0[2]*d0[2];
    float e11 = d1[0]*d1[0] + d1[1]*d1[1] + d1[2]*d1[2];
    float e22 = d2[0]*d2[0] + d2[1]*d2[1] + d2[2]*d2[2];
    float e01 = d0[0]*d1[0] + d0[1]*d1[1] + d0[2]*d1[2];
    float e02 = d0[0]*d2[0] + d0[1]*d2[1] + d0[2]*d2[2];
    float e12 = d1[0]*d2[0] + d1[1]*d2[1] + d1[2]*d2[2];
    float s0 = sqrtf(e00), s1 = sqrtf(e11), s2 = sqrtf(e22);

    int cc = 0;
    {
        float ne;
        ne = e00 / (s0*s0 + 1e-8f); cc += (ne > DC) || (ne < -DC);
        ne = e11 / (s1*s1 + 1e-8f); cc += (ne > DC) || (ne < -DC);
        ne = e22 / (s2*s2 + 1e-8f); cc += (ne > DC) || (ne < -DC);
        ne = e01 / (s0*s1 + 1e-8f); cc += 2 * ((ne > DC) || (ne < -DC));
        ne = e02 / (s0*s2 + 1e-8f); cc += 2 * ((ne > DC) || (ne < -DC));
        ne = e12 / (s1*s2 + 1e-8f); cc += 2 * ((ne > DC) || (ne < -DC));
    }
    bool mask_cos = cc > 3;
    bool mask_pad = (G1[2] > DZ) && (G2[2] > DZ) && (G3[2] > DZ);
    bool mx = (fabsf(d0[0]) < DD) || (fabsf(d1[0]) < DD) || (fabsf(d2[0]) < DD);
    bool my = (fabsf(d0[1]) < DD) || (fabsf(d1[1]) < DD) || (fabsf(d2[1]) < DD);
    bool mz = (fabsf(d0[2]) < DD) || (fabsf(d1[2]) < DD) || (fabsf(d2[2]) < DD);
    bool mask = mask_pad && !((mx && my && mz) || mask_cos);

    if (mask) {
        float n0 = d0[1]*d1[2] - d0[2]*d1[1];
        float n1 = d0[2]*d1[0] - d0[0]*d1[2];
        float n2 = d0[0]*d1[1] - d0[1]*d1[0];
        float nn = sqrtf(n0*n0 + n1*n1 + n2*n2);
        if (nn == 0.f) nn = 0.01f;

        // bug-faithful zmask broadcast: mask indexed by POINT, applied on CHANNEL
        bool zm[3] = { P1[2] == 0.f, P2[2] == 0.f, P3[2] == 0.f };
        float Q1[3], Q2[3], Q3[3];
        #pragma unroll
        for (int c = 0; c < 3; c++) {
            Q1[c] = zm[c] ? 0.0001f : P1[c];
            Q2[c] = zm[c] ? 0.0001f : P2[c];
            Q3[c] = zm[c] ? 0.0001f : P3[c];
        }
        float q0[3], q1[3];
        #pragma unroll
        for (int c = 0; c < 3; c++) {
            q0[c] = Q2[c] - Q1[c];
            q1[c] = Q3[c] - Q1[c];
        }
        float m0 = q0[1]*q1[2] - q0[2]*q1[1];
        float m1 = q0[2]*q1[0] - q0[0]*q1[2];
        float m2 = q0[0]*q1[1] - q0[1]*q1[0];
        float mn = sqrtf(m0*m0 + m1*m1 + m2*m2);
        if (mn == 0.f) mn = 0.01f;

        s_loss += fabsf(n0/nn - m0/mn) + fabsf(n1/nn - m1/mn) + fabsf(n2/nn - m2/mn);
        s_cnt  += 1.f;
    }
}

__device__ __forceinline__ void vn_reduce_store(float s_loss, float s_cnt, double* acc)
{
    #pragma unroll
    for (int off = 32; off > 0; off >>= 1) {
        s_loss += __shfl_down(s_loss, off);
        s_cnt  += __shfl_down(s_cnt,  off);
    }
    __shared__ float ls[4], lc[4];
    int lane = threadIdx.x & 63;
    int wid  = threadIdx.x >> 6;
    if (lane == 0) { ls[wid] = s_loss; lc[wid] = s_cnt; }
    __syncthreads();
    if (threadIdx.x == 0) {
        float tl = ls[0] + ls[1] + ls[2] + ls[3];
        float tc = lc[0] + lc[1] + lc[2] + lc[3];
        atomicAdd(acc,     (double)tl);
        atomicAdd(acc + 1, (double)tc);
    }
}

// ---------------- pack: plane-major f32 -> [pixel][batch] f16 16B records --
// rec[pix*8 + b] = uint4{ h2(gt0,gt1), h2(gt2,pr0), h2(pr1,pr2), 0 }
// batch in tid&7 so consecutive lanes write consecutive records (coalesced).
__global__ __launch_bounds__(256) void vn_pack_h(
    const float* __restrict__ gt, const float* __restrict__ pred,
    uint4* __restrict__ rec)
{
    size_t tid = (size_t)blockIdx.x * 256 + threadIdx.x;   // [0, HW*8)
    int    b   = (int)(tid & 7);
    size_t i   = tid >> 3;

    const float* gb = gt   + (size_t)b * 3 * HW_ + i;
    const float* pb = pred + (size_t)b * 3 * HW_ + i;
    float g0 = gb[0], g1 = gb[HW_], g2 = gb[2 * (size_t)HW_];
    float p0 = pb[0], p1 = pb[HW_], p2 = pb[2 * (size_t)HW_];

    uint4 o;
    __half2* h = (__half2*)&o;
    h[0] = __floats2half2_rn(g0, g1);
    h[1] = __floats2half2_rn(g2, p0);
    h[2] = __floats2half2_rn(p1, p2);
    h[3] = __floats2half2_rn(0.f, 0.f);
    rec[i * 8 + b] = o;
}

__device__ __forceinline__ void unpack_rec(uint4 r, float G[3], float P[3])
{
    __half2 a = *(__half2*)&r.x;
    __half2 b = *(__half2*)&r.y;
    __half2 c = *(__half2*)&r.z;
    G[0] = __low2float(a);  G[1] = __high2float(a);
    G[2] = __low2float(b);  P[0] = __high2float(b);
    P[1] = __low2float(c);  P[2] = __high2float(c);
}

// ---------------- gather: 2 threads per group, 4 batches each --------------
// Each point's 4-batch block = 64B contiguous, fully used.
__global__ __launch_bounds__(256) void vn_gather_h(
    const uint4* __restrict__ rec,
    const int* __restrict__ p1x, const int* __restrict__ p1y,
    const int* __restrict__ p2x, const int* __restrict__ p2y,
    const int* __restrict__ p3x, const int* __restrict__ p3y,
    int G, double* __restrict__ acc)
{
    int t = blockIdx.x * 256 + threadIdx.x;
    int g = t >> 1;
    int h = (t & 1) * 4;          // batches [h, h+4)

    float s_loss = 0.f, s_cnt = 0.f;

    if (g < G) {
        size_t q1 = ((size_t)(p1y[g] * W_ + p1x[g])) * 8 + h;
        size_t q2 = ((size_t)(p2y[g] * W_ + p2x[g])) * 8 + h;
        size_t q3 = ((size_t)(p3y[g] * W_ + p3x[g])) * 8 + h;

        uint4 r1[4], r2[4], r3[4];
        #pragma unroll
        for (int j = 0; j < 4; j++) r1[j] = rec[q1 + j];
        #pragma unroll
        for (int j = 0; j < 4; j++) r2[j] = rec[q2 + j];
        #pragma unroll
        for (int j = 0; j < 4; j++) r3[j] = rec[q3 + j];

        #pragma unroll
        for (int j = 0; j < 4; j++) {
            float G1[3], P1[3], G2[3], P2[3], G3[3], P3[3];
            unpack_rec(r1[j], G1, P1);
            unpack_rec(r2[j], G2, P2);
            unpack_rec(r3[j], G3, P3);
            vn_group_math(G1, G2, G3, P1, P2, P3, s_loss, s_cnt);
        }
    }

    vn_reduce_store(s_loss, s_cnt, acc);
}

// ---------------- fallback: direct gather from plane-major (f32 exact) -----
__global__ __launch_bounds__(256) void vn_main(
    const float* __restrict__ gt, const float* __restrict__ pred,
    const int* __restrict__ p1x, const int* __restrict__ p1y,
    const int* __restrict__ p2x, const int* __restrict__ p2y,
    const int* __restrict__ p3x, const int* __restrict__ p3y,
    int G, double* __restrict__ acc)
{
    int g = blockIdx.x * 256 + threadIdx.x;
    int b = blockIdx.y;

    float s_loss = 0.f, s_cnt = 0.f;

    if (g < G) {
        int o1 = p1y[g] * W_ + p1x[g];
        int o2 = p2y[g] * W_ + p2x[g];
        int o3 = p3y[g] * W_ + p3x[g];
        const float* gb = gt   + (size_t)b * 3 * HW_;
        const float* pb = pred + (size_t)b * 3 * HW_;

        float G1[3], G2[3], G3[3], P1[3], P2[3], P3[3];
        #pragma unroll
        for (int c = 0; c < 3; c++) {
            G1[c] = gb[c * HW_ + o1];
            G2[c] = gb[c * HW_ + o2];
            G3[c] = gb[c * HW_ + o3];
            P1[c] = pb[c * HW_ + o1];
            P2[c] = pb[c * HW_ + o2];
            P3[c] = pb[c * HW_ + o3];
        }
        vn_group_math(G1, G2, G3, P1, P2, P3, s_loss, s_cnt);
    }

    vn_reduce_store(s_loss, s_cnt, acc);
}

__global__ void vn_final(const double* __restrict__ acc, float* __restrict__ out)
{
    float s = (float)acc[0];
    float c = (float)acc[1];
    out[0] = s / fmaxf(c, 1.0f);
}

extern "C" void kernel_launch(void* const* d_in, const int* in_sizes, int n_in,
                              void* d_out, int out_size, void* d_ws, size_t ws_size,
                              hipStream_t stream) {
    const float* gt   = (const float*)d_in[0];
    const float* pred = (const float*)d_in[1];
    const int* p1x = (const int*)d_in[2];
    const int* p1y = (const int*)d_in[3];
    const int* p2x = (const int*)d_in[4];
    const int* p2y = (const int*)d_in[5];
    const int* p3x = (const int*)d_in[6];
    const int* p3y = (const int*)d_in[7];

    int G = in_sizes[2];
    int B = in_sizes[0] / (3 * HW_);
    double* acc = (double*)d_ws;

    hipMemsetAsync(acc, 0, 2 * sizeof(double), stream);

    size_t rec_bytes = (size_t)HW_ * 8 * sizeof(uint4);    // 16B per (pixel,batch)
    size_t need = 256 + rec_bytes;

    if (B == 8 && ws_size >= need) {
        uint4* rec = (uint4*)((char*)d_ws + 256);
        int pack_blocks = (int)(((size_t)HW_ * 8) / 256);
        vn_pack_h<<<pack_blocks, 256, 0, stream>>>(gt, pred, rec);
        int nthreads = G * 2;                              // 2 threads per group
        vn_gather_h<<<(nthreads + 255) / 256, 256, 0, stream>>>(
            rec, p1x, p1y, p2x, p2y, p3x, p3y, G, acc);
    } else {
        dim3 grid((G + 255) / 256, B);
        vn_main<<<grid, 256, 0, stream>>>(gt, pred, p1x, p1y, p2x, p2y, p3x, p3y, G, acc);
    }

    vn_final<<<1, 1, 0, stream>>>(acc, (float*)d_out);
}

// Round 5
// 78.408 us; speedup vs baseline: 3.2063x; 1.0624x over previous
//
#include <hip/hip_runtime.h>
#include <hip/hip_fp16.h>

#define HW_ (768 * 1024)
#define W_ 1024
#define DC 0.867f
#define DD 0.005f
#define DZ 0.0001f

#define SEG_STRIDE 260   // halfs per (batch,channel) segment in LDS (bank-safe, 8B-aligned)

// ---------------- shared group math (ACCUMULATES into s_loss/s_cnt) -------
__device__ __forceinline__ void vn_group_math(
    const float G1[3], const float G2[3], const float G3[3],
    const float P1[3], const float P2[3], const float P3[3],
    float& s_loss, float& s_cnt)
{
    float d0[3], d1[3], d2[3];
    #pragma unroll
    for (int c = 0; c < 3; c++) {
        d0[c] = G2[c] - G1[c];
        d1[c] = G3[c] - G1[c];
        d2[c] = G3[c] - G2[c];
    }

    float e00 = d0[0]*d0[0] + d0[1]*d0[1] + d0[2]*d0[2];
    float e11 = d1[0]*d1[0] + d1[1]*d1[1] + d1[2]*d1[2];
    float e22 = d2[0]*d2[0] + d2[1]*d2[1] + d2[2]*d2[2];
    float e01 = d0[0]*d1[0] + d0[1]*d1[1] + d0[2]*d1[2];
    float e02 = d0[0]*d2[0] + d0[1]*d2[1] + d0[2]*d2[2];
    float e12 = d1[0]*d2[0] + d1[1]*d2[1] + d1[2]*d2[2];
    float s0 = sqrtf(e00), s1 = sqrtf(e11), s2 = sqrtf(e22);

    int cc = 0;
    {
        float ne;
        ne = e00 / (s0*s0 + 1e-8f); cc += (ne > DC) || (ne < -DC);
        ne = e11 / (s1*s1 + 1e-8f); cc += (ne > DC) || (ne < -DC);
        ne = e22 / (s2*s2 + 1e-8f); cc += (ne > DC) || (ne < -DC);
        ne = e01 / (s0*s1 + 1e-8f); cc += 2 * ((ne > DC) || (ne < -DC));
        ne = e02 / (s0*s2 + 1e-8f); cc += 2 * ((ne > DC) || (ne < -DC));
        ne = e12 / (s1*s2 + 1e-8f); cc += 2 * ((ne > DC) || (ne < -DC));
    }
    bool mask_cos = cc > 3;
    bool mask_pad = (G1[2] > DZ) && (G2[2] > DZ) && (G3[2] > DZ);
    bool mx = (fabsf(d0[0]) < DD) || (fabsf(d1[0]) < DD) || (fabsf(d2[0]) < DD);
    bool my = (fabsf(d0[1]) < DD) || (fabsf(d1[1]) < DD) || (fabsf(d2[1]) < DD);
    bool mz = (fabsf(d0[2]) < DD) || (fabsf(d1[2]) < DD) || (fabsf(d2[2]) < DD);
    bool mask = mask_pad && !((mx && my && mz) || mask_cos);

    if (mask) {
        float n0 = d0[1]*d1[2] - d0[2]*d1[1];
        float n1 = d0[2]*d1[0] - d0[0]*d1[2];
        float n2 = d0[0]*d1[1] - d0[1]*d1[0];
        float nn = sqrtf(n0*n0 + n1*n1 + n2*n2);
        if (nn == 0.f) nn = 0.01f;

        // bug-faithful zmask broadcast: mask indexed by POINT, applied on CHANNEL
        bool zm[3] = { P1[2] == 0.f, P2[2] == 0.f, P3[2] == 0.f };
        float Q1[3], Q2[3], Q3[3];
        #pragma unroll
        for (int c = 0; c < 3; c++) {
            Q1[c] = zm[c] ? 0.0001f : P1[c];
            Q2[c] = zm[c] ? 0.0001f : P2[c];
            Q3[c] = zm[c] ? 0.0001f : P3[c];
        }
        float q0[3], q1[3];
        #pragma unroll
        for (int c = 0; c < 3; c++) {
            q0[c] = Q2[c] - Q1[c];
            q1[c] = Q3[c] - Q1[c];
        }
        float m0 = q0[1]*q1[2] - q0[2]*q1[1];
        float m1 = q0[2]*q1[0] - q0[0]*q1[2];
        float m2 = q0[0]*q1[1] - q0[1]*q1[0];
        float mn = sqrtf(m0*m0 + m1*m1 + m2*m2);
        if (mn == 0.f) mn = 0.01f;

        s_loss += fabsf(n0/nn - m0/mn) + fabsf(n1/nn - m1/mn) + fabsf(n2/nn - m2/mn);
        s_cnt  += 1.f;
    }
}

__device__ __forceinline__ void vn_reduce_store(float s_loss, float s_cnt, double* acc)
{
    #pragma unroll
    for (int off = 32; off > 0; off >>= 1) {
        s_loss += __shfl_down(s_loss, off);
        s_cnt  += __shfl_down(s_cnt,  off);
    }
    __shared__ float ls[4], lc[4];
    int lane = threadIdx.x & 63;
    int wid  = threadIdx.x >> 6;
    if (lane == 0) { ls[wid] = s_loss; lc[wid] = s_cnt; }
    __syncthreads();
    if (threadIdx.x == 0) {
        float tl = ls[0] + ls[1] + ls[2] + ls[3];
        float tc = lc[0] + lc[1] + lc[2] + lc[3];
        atomicAdd(acc,     (double)tl);
        atomicAdd(acc + 1, (double)tc);
    }
}

// ---------------- pack via LDS transpose ----------------------------------
// Tile: 256 pixels x 8 batches. Phase 1: float4 coalesced plane reads ->
// f16 in LDS (48 segments of SEG_STRIDE halfs). Phase 2: assemble 16B
// records, store so each wave-store is 1KB contiguous.
// rec[pix*8 + b] = uint4{ h2(gt0,gt1), h2(gt2,pr0), h2(pr1,pr2), 0 }
__global__ __launch_bounds__(256) void vn_pack_t(
    const float* __restrict__ gt, const float* __restrict__ pred,
    uint4* __restrict__ rec)
{
    __shared__ __half lh[48 * SEG_STRIDE];   // ~25 KB

    size_t px_base = (size_t)blockIdx.x * 256;
    int t = threadIdx.x;
    int w = t >> 6, l = t & 63;

    // phase 1: each wave loads 12 segments; one 1KB contiguous segment per inst
    #pragma unroll
    for (int k = 0; k < 12; k++) {
        int s = w * 12 + k;              // s = b*6 + c
        int b = s / 6, c = s % 6;
        const float* src = (c < 3)
            ? gt   + ((size_t)b * 3 + c)       * HW_ + px_base
            : pred + ((size_t)b * 3 + (c - 3)) * HW_ + px_base;
        float4 v = *(const float4*)(src + l * 4);
        __half2 v01 = __floats2half2_rn(v.x, v.y);
        __half2 v23 = __floats2half2_rn(v.z, v.w);
        uint2 pk;
        pk.x = *(unsigned int*)&v01;
        pk.y = *(unsigned int*)&v23;
        *(uint2*)(&lh[(size_t)s * SEG_STRIDE + l * 4]) = pk;
    }

    __syncthreads();

    // phase 2: 8 records/thread; record j = t + r*256 -> 1KB contiguous stores
    int b  = t & 7;
    int c6 = b * 6;
    uint4* out = rec + px_base * 8;
    #pragma unroll
    for (int r = 0; r < 8; r++) {
        int j    = t + r * 256;
        int i_px = j >> 3;               // == (t>>3) + r*32
        uint4 o;
        __half2* hh = (__half2*)&o;
        hh[0] = __halves2half2(lh[(c6 + 0) * SEG_STRIDE + i_px],
                               lh[(c6 + 1) * SEG_STRIDE + i_px]);
        hh[1] = __halves2half2(lh[(c6 + 2) * SEG_STRIDE + i_px],
                               lh[(c6 + 3) * SEG_STRIDE + i_px]);
        hh[2] = __halves2half2(lh[(c6 + 4) * SEG_STRIDE + i_px],
                               lh[(c6 + 5) * SEG_STRIDE + i_px]);
        o.w = 0u;
        out[j] = o;
    }
}

__device__ __forceinline__ void unpack_rec(uint4 r, float G[3], float P[3])
{
    __half2 a = *(__half2*)&r.x;
    __half2 b = *(__half2*)&r.y;
    __half2 c = *(__half2*)&r.z;
    G[0] = __low2float(a);  G[1] = __high2float(a);
    G[2] = __low2float(b);  P[0] = __high2float(b);
    P[1] = __low2float(c);  P[2] = __high2float(c);
}

// ---------------- gather: 2 threads per group, 4 batches each --------------
__global__ __launch_bounds__(256) void vn_gather_h(
    const uint4* __restrict__ rec,
    const int* __restrict__ p1x, const int* __restrict__ p1y,
    const int* __restrict__ p2x, const int* __restrict__ p2y,
    const int* __restrict__ p3x, const int* __restrict__ p3y,
    int G, double* __restrict__ acc)
{
    int t = blockIdx.x * 256 + threadIdx.x;
    int g = t >> 1;
    int h = (t & 1) * 4;          // batches [h, h+4)

    float s_loss = 0.f, s_cnt = 0.f;

    if (g < G) {
        size_t q1 = ((size_t)(p1y[g] * W_ + p1x[g])) * 8 + h;
        size_t q2 = ((size_t)(p2y[g] * W_ + p2x[g])) * 8 + h;
        size_t q3 = ((size_t)(p3y[g] * W_ + p3x[g])) * 8 + h;

        uint4 r1[4], r2[4], r3[4];
        #pragma unroll
        for (int j = 0; j < 4; j++) r1[j] = rec[q1 + j];
        #pragma unroll
        for (int j = 0; j < 4; j++) r2[j] = rec[q2 + j];
        #pragma unroll
        for (int j = 0; j < 4; j++) r3[j] = rec[q3 + j];

        #pragma unroll
        for (int j = 0; j < 4; j++) {
            float G1[3], P1[3], G2[3], P2[3], G3[3], P3[3];
            unpack_rec(r1[j], G1, P1);
            unpack_rec(r2[j], G2, P2);
            unpack_rec(r3[j], G3, P3);
            vn_group_math(G1, G2, G3, P1, P2, P3, s_loss, s_cnt);
        }
    }

    vn_reduce_store(s_loss, s_cnt, acc);
}

// ---------------- fallback: direct gather from plane-major (f32 exact) -----
__global__ __launch_bounds__(256) void vn_main(
    const float* __restrict__ gt, const float* __restrict__ pred,
    const int* __restrict__ p1x, const int* __restrict__ p1y,
    const int* __restrict__ p2x, const int* __restrict__ p2y,
    const int* __restrict__ p3x, const int* __restrict__ p3y,
    int G, double* __restrict__ acc)
{
    int g = blockIdx.x * 256 + threadIdx.x;
    int b = blockIdx.y;

    float s_loss = 0.f, s_cnt = 0.f;

    if (g < G) {
        int o1 = p1y[g] * W_ + p1x[g];
        int o2 = p2y[g] * W_ + p2x[g];
        int o3 = p3y[g] * W_ + p3x[g];
        const float* gb = gt   + (size_t)b * 3 * HW_;
        const float* pb = pred + (size_t)b * 3 * HW_;

        float G1[3], G2[3], G3[3], P1[3], P2[3], P3[3];
        #pragma unroll
        for (int c = 0; c < 3; c++) {
            G1[c] = gb[c * HW_ + o1];
            G2[c] = gb[c * HW_ + o2];
            G3[c] = gb[c * HW_ + o3];
            P1[c] = pb[c * HW_ + o1];
            P2[c] = pb[c * HW_ + o2];
            P3[c] = pb[c * HW_ + o3];
        }
        vn_group_math(G1, G2, G3, P1, P2, P3, s_loss, s_cnt);
    }

    vn_reduce_store(s_loss, s_cnt, acc);
}

__global__ void vn_final(const double* __restrict__ acc, float* __restrict__ out)
{
    float s = (float)acc[0];
    float c = (float)acc[1];
    out[0] = s / fmaxf(c, 1.0f);
}

extern "C" void kernel_launch(void* const* d_in, const int* in_sizes, int n_in,
                              void* d_out, int out_size, void* d_ws, size_t ws_size,
                              hipStream_t stream) {
    const float* gt   = (const float*)d_in[0];
    const float* pred = (const float*)d_in[1];
    const int* p1x = (const int*)d_in[2];
    const int* p1y = (const int*)d_in[3];
    const int* p2x = (const int*)d_in[4];
    const int* p2y = (const int*)d_in[5];
    const int* p3x = (const int*)d_in[6];
    const int* p3y = (const int*)d_in[7];

    int G = in_sizes[2];
    int B = in_sizes[0] / (3 * HW_);
    double* acc = (double*)d_ws;

    hipMemsetAsync(acc, 0, 2 * sizeof(double), stream);

    size_t rec_bytes = (size_t)HW_ * 8 * sizeof(uint4);    // 16B per (pixel,batch)
    size_t need = 256 + rec_bytes;

    if (B == 8 && ws_size >= need) {
        uint4* rec = (uint4*)((char*)d_ws + 256);
        vn_pack_t<<<HW_ / 256, 256, 0, stream>>>(gt, pred, rec);
        int nthreads = G * 2;                              // 2 threads per group
        vn_gather_h<<<(nthreads + 255) / 256, 256, 0, stream>>>(
            rec, p1x, p1y, p2x, p2y, p3x, p3y, G, acc);
    } else {
        dim3 grid((G + 255) / 256, B);
        vn_main<<<grid, 256, 0, stream>>>(gt, pred, p1x, p1y, p2x, p2y, p3x, p3y, G, acc);
    }

    vn_final<<<1, 1, 0, stream>>>(acc, (float*)d_out);
}